// Round 1
// 667.365 us; speedup vs baseline: 1.0170x; 1.0170x over previous
//
#include <hip/hip_runtime.h>
#include <cmath>

#define T_TOK 8192
#define N_EXP 256
#define HID   7168
#define KHALF 3584
#define RESCUE_CAP 2048
#define MTAU 4e-5     // expert-chain margin threshold (score space), ~3x the 5-sigma bf16-split error
#define GTAU 1.6e-4   // group-sum margin threshold (= 4*MTAU)

typedef unsigned short u16;
typedef short bf16x8 __attribute__((ext_vector_type(8)));
typedef short s16x4 __attribute__((ext_vector_type(4)));
typedef float f32x4 __attribute__((ext_vector_type(4)));
typedef double f64x4 __attribute__((ext_vector_type(4)));

typedef const __attribute__((address_space(1))) unsigned int* gas_ptr;
typedef __attribute__((address_space(3))) unsigned int* las_ptr;

__device__ __forceinline__ u16 bf16_rtne(float f) {
    unsigned u = __float_as_uint(f);
    u += 0x7FFFu + ((u >> 16) & 1u);
    return (u16)(u >> 16);
}
__device__ __forceinline__ float bf16_f(u16 h) { return __uint_as_float(((unsigned)h) << 16); }

// fp32 -> (hi,lo) bf16 pair; identical rounding to v8's wsplit (hi = rtne, lo = rtne(f - hi))
__device__ __forceinline__ void cvt8(float4 a, float4 b, bf16x8& H, bf16x8& L) {
    const float f[8] = {a.x, a.y, a.z, a.w, b.x, b.y, b.z, b.w};
#pragma unroll
    for (int i = 0; i < 8; ++i) {
        unsigned u = __float_as_uint(f[i]);
        unsigned r = u + (0x7FFFu + ((u >> 16) & 1u));
        H[i] = (short)(r >> 16);
        const float hif = __uint_as_float(r & 0xFFFF0000u);
        L[i] = (short)bf16_rtne(f[i] - hif);
    }
}

// LDS tile [rows][32 bf16] with per-row XOR swizzle of the 16B chunk index:
// physical chunk = c16 ^ ((row>>1)&3). Makes every b128 read/write <=2-way (free).
__device__ __forceinline__ int swz(int row, int c16) {
    return row * 32 + (((c16 ^ (row >> 1)) & 3) << 3);
}

__device__ __forceinline__ void gload16(const void* g, void* l) {
    __builtin_amdgcn_global_load_lds((gas_ptr)g, (las_ptr)l, 16, 0, 0);
}

__global__ void zero_cnt(int* cnt) { if (threadIdx.x == 0) *cnt = 0; }

__global__ __launch_bounds__(256)
void zero_logits(float* __restrict__ p) {
    const size_t i = ((size_t)blockIdx.x * 256 + threadIdx.x) * 4;
    *(float4*)(p + i) = make_float4(0.f, 0.f, 0.f, 0.f);
}

// ---------------------------------------------------------------------------
// K1: split w fp32 -> (wh, wl) bf16 pair. Exact: wl = bf16(w - float(wh)).
// ---------------------------------------------------------------------------
__global__ __launch_bounds__(256)
void wsplit(const float* __restrict__ w, u16* __restrict__ wh, u16* __restrict__ wl)
{
    const size_t base = ((size_t)blockIdx.x * 256 + threadIdx.x) * 8;
    const float4 f0 = *(const float4*)(w + base);
    const float4 f1 = *(const float4*)(w + base + 4);
    const float f[8] = {f0.x, f0.y, f0.z, f0.w, f1.x, f1.y, f1.z, f1.w};
    bf16x8 H, L;
#pragma unroll
    for (int i = 0; i < 8; ++i) {
        const u16 h = bf16_rtne(f[i]);
        H[i] = (short)h;
        L[i] = (short)bf16_rtne(f[i] - bf16_f(h));
    }
    *(bf16x8*)(wh + base) = H;
    *(bf16x8*)(wl + base) = L;
}

// ---------------------------------------------------------------------------
// K2 v9: bf16-split GEMM restructured.
//  - BM=128 x BN=64, BK=32, 4 waves (2M x 2N), wave tile 64x32:
//    24 MFMA per 12 ds_read_b128 (2:1, was 1.5:1).
//  - K-split x2 -> 512 blocks = 2/CU; partials combined via atomicAdd onto
//    pre-zeroed logits (exactly 2 commutative fp32 adds/cell -> deterministic).
//  - x: reg-prefetch + fp32->hi/lo conversion OVERLAPPED with MFMA phase;
//    stage phase is only 4x ds_write_b128.
//  - wh/wl: global_load_lds width=16 (linear dest, source-side pre-swizzle).
//  - XOR chunk swizzle on all tiles -> 2-way (free) LDS access by design.
//  - XCD-grouped mapping: the 8 (col,kz) blocks of one token slab share an XCD
//    so x is fetched from HBM once.
// ---------------------------------------------------------------------------
__global__ __launch_bounds__(256, 2)
void gemm_bf16split_v9(const float* __restrict__ x, const u16* __restrict__ wh,
                       const u16* __restrict__ wl, float* __restrict__ logits)
{
    __shared__ u16 sxh[128 * 32], sxl[128 * 32], swh[64 * 32], swl[64 * 32];
    const int tid = threadIdx.x;
    const int wave = tid >> 6, lane = tid & 63;

    // block mapping: h%8 selects slab-group lane -> slab j handled by XCD j&7
    const int h = blockIdx.x;
    const int cc8 = (h >> 3) & 7;              // 8 blocks per slab
    const int col = cc8 & 3, kz = cc8 >> 2;    // 4 expert cols x 2 k-halves
    const int slab = (h & 7) | ((h >> 6) << 3);
    const int t0 = slab * 128;
    const int e0 = col * 64;
    const int kbase = kz * KHALF;

    const int la = lane & 15, q = lane >> 4;

    // calibration probes: decode C/D reg->(row,col) on-device (v8-proven)
    bf16x8 pidx = (bf16x8)(short)0, pone = (bf16x8)(short)0;
    if (q == 0) {
        pidx[0] = (short)bf16_rtne((float)la);
        pone[0] = (short)0x3F80;
    }
    f32x4 pr = __builtin_amdgcn_mfma_f32_16x16x32_bf16(pidx, pone, (f32x4)(0.f), 0, 0, 0);
    f32x4 pc = __builtin_amdgcn_mfma_f32_16x16x32_bf16(pone, pidx, (f32x4)(0.f), 0, 0, 0);
    int rrow[4], rcol[4];
#pragma unroll
    for (int i = 0; i < 4; ++i) {
        rrow[i] = (int)(pr[i] + 0.5f);
        rcol[i] = (int)(pc[i] + 0.5f);
    }

    // x staging coords: thread -> row sr (0..127), k-half halfk (16 floats)
    const int sr = tid >> 1, halfk = tid & 1;
    const float* xp = x + (size_t)(t0 + sr) * HID + kbase + halfk * 16;

    // w staging via global_load_lds: dest = wave-uniform base + lane*16
    // lane's LDS slot: row = wave*16 + (lane>>2), chunk = lane&3;
    // source chunk pre-swizzled so swizzled reads retrieve logical data.
    const int wlr = wave * 16 + (lane >> 2);
    const int wgc = (lane & 3) ^ ((wlr >> 1) & 3);
    const u16* whp = wh + (size_t)(e0 + wlr) * HID + kbase + wgc * 8;
    const u16* wlp = wl + (size_t)(e0 + wlr) * HID + kbase + wgc * 8;
    u16* swh_base = &swh[wave * 512];
    u16* swl_base = &swl[wave * 512];

    f32x4 acc[4][2];
#pragma unroll
    for (int i = 0; i < 4; ++i)
#pragma unroll
        for (int j = 0; j < 2; ++j) acc[i][j] = (f32x4)(0.f);

    const int m0 = (wave >> 1) * 64;
    const int n0 = (wave & 1) * 32;

    // prologue: load + convert tile 0 into registers
    bf16x8 XH0, XH1, XL0, XL1;
    {
        float4 a = *(const float4*)xp,       b = *(const float4*)(xp + 4);
        float4 c = *(const float4*)(xp + 8), d = *(const float4*)(xp + 12);
        cvt8(a, b, XH0, XL0);
        cvt8(c, d, XH1, XL1);
    }

    for (int k0 = 0; k0 < KHALF; k0 += 32) {
        __syncthreads();
        // stage x from pre-converted regs (4x ds_write_b128, swizzled)
        *(bf16x8*)&sxh[swz(sr, 2 * halfk)]     = XH0;
        *(bf16x8*)&sxh[swz(sr, 2 * halfk + 1)] = XH1;
        *(bf16x8*)&sxl[swz(sr, 2 * halfk)]     = XL0;
        *(bf16x8*)&sxl[swz(sr, 2 * halfk + 1)] = XL1;
        // stage w direct-to-LDS (vmcnt drained by next __syncthreads)
        gload16(whp + k0, swh_base);
        gload16(wlp + k0, swl_base);
        __syncthreads();
        // prefetch + convert NEXT x tile: VALU overlaps the MFMA block below
        if (k0 + 32 < KHALF) {
            const float* p = xp + k0 + 32;
            float4 a = *(const float4*)p,       b = *(const float4*)(p + 4);
            float4 c = *(const float4*)(p + 8), d = *(const float4*)(p + 12);
            cvt8(a, b, XH0, XL0);
            cvt8(c, d, XH1, XL1);
        }
        bf16x8 Ah[4], Al[4], Bh[2], Bl[2];
#pragma unroll
        for (int mi = 0; mi < 4; ++mi) {
            const int r = m0 + 16 * mi + la;
            Ah[mi] = *(const bf16x8*)&sxh[swz(r, q)];
            Al[mi] = *(const bf16x8*)&sxl[swz(r, q)];
        }
#pragma unroll
        for (int ni = 0; ni < 2; ++ni) {
            const int r = n0 + 16 * ni + la;
            Bh[ni] = *(const bf16x8*)&swh[swz(r, q)];
            Bl[ni] = *(const bf16x8*)&swl[swz(r, q)];
        }
#pragma unroll
        for (int mi = 0; mi < 4; ++mi)
#pragma unroll
            for (int ni = 0; ni < 2; ++ni) {
                acc[mi][ni] = __builtin_amdgcn_mfma_f32_16x16x32_bf16(Ah[mi], Bh[ni], acc[mi][ni], 0, 0, 0);
                acc[mi][ni] = __builtin_amdgcn_mfma_f32_16x16x32_bf16(Ah[mi], Bl[ni], acc[mi][ni], 0, 0, 0);
                acc[mi][ni] = __builtin_amdgcn_mfma_f32_16x16x32_bf16(Al[mi], Bh[ni], acc[mi][ni], 0, 0, 0);
            }
    }

    // k-split combine: exactly 2 contributions per cell onto zeroed memory;
    // fp32 add is commutative -> bitwise deterministic.
#pragma unroll
    for (int mi = 0; mi < 4; ++mi)
#pragma unroll
        for (int ni = 0; ni < 2; ++ni)
#pragma unroll
            for (int i = 0; i < 4; ++i)
                atomicAdd(&logits[(size_t)(t0 + m0 + 16 * mi + rrow[i]) * N_EXP + e0 + n0 + 16 * ni + rcol[i]],
                          acc[mi][ni][i]);
}

// ---------------------------------------------------------------------------
// K3: routing + margin flags (verbatim r7-proven).
// ---------------------------------------------------------------------------
__global__ __launch_bounds__(256)
void route_flag(const float* __restrict__ logits, const float* __restrict__ bias,
                float* __restrict__ out_idx, float* __restrict__ out_w,
                int* __restrict__ cnt, int* __restrict__ list)
{
    const int wave = threadIdx.x >> 6;
    const int lane = threadIdx.x & 63;
    const int t = blockIdx.x * 4 + wave;

    const float4 lg = *(const float4*)(logits + (size_t)t * N_EXP + 4 * lane);
    const float4 bf = *(const float4*)(bias + 4 * lane);
    const float lgv[4] = {lg.x, lg.y, lg.z, lg.w};
    const float bfv[4] = {bf.x, bf.y, bf.z, bf.w};
    double raw[4], v[4];
#pragma unroll
    for (int j = 0; j < 4; ++j) {
        raw[j] = 1.0 / (1.0 + exp(-(double)lgv[j]));
        v[j] = raw[j] + (double)bfv[j];
    }

    double m1 = -1e300, m2 = -1e300;
#pragma unroll
    for (int j = 0; j < 4; ++j) {
        if (v[j] > m1) { m2 = m1; m1 = v[j]; }
        else if (v[j] > m2) { m2 = v[j]; }
    }
#pragma unroll
    for (int d = 1; d <= 4; d <<= 1) {
        const double o1 = __shfl_xor(m1, d);
        const double o2 = __shfl_xor(m2, d);
        if (o1 > m1) { m2 = fmax(m1, o2); m1 = o1; }
        else         { m2 = fmax(m2, o1); }
    }
    const double gsum = m1 + m2;

    double gq[8];
#pragma unroll
    for (int g = 0; g < 8; ++g) gq[g] = __shfl(gsum, g * 8);
    int gm = 0;
    double g4v = -1e300, gmargin = 1e300;
#pragma unroll
    for (int rr = 0; rr < 5; ++rr) {
        int best = 0; double bv = -1e300;
#pragma unroll
        for (int g = 0; g < 8; ++g) {
            const bool taken = (gm >> g) & 1;
            if (!taken && gq[g] > bv) { bv = gq[g]; best = g; }
        }
        if (rr < 4) { gm |= (1 << best); g4v = bv; }
        else gmargin = g4v - bv;
    }

    double cv[4];
    const bool inmask = (gm >> (lane >> 3)) & 1;
#pragma unroll
    for (int j = 0; j < 4; ++j) cv[j] = inmask ? v[j] : 0.0;

    double wsum = 0.0, my_w = 0.0, prev = 0.0, mmin = 1e300;
    int my_i = 0;
#pragma unroll
    for (int rr = 0; rr < 9; ++rr) {
        double bv = cv[0]; int bj = 0;
#pragma unroll
        for (int j = 1; j < 4; ++j)
            if (cv[j] > bv) { bv = cv[j]; bj = j; }
        int bi = 4 * lane + bj;
        double braw = (bj == 0) ? raw[0] : (bj == 1) ? raw[1] : (bj == 2) ? raw[2] : raw[3];
#pragma unroll
        for (int d = 1; d < 64; d <<= 1) {
            const double ov  = __shfl_xor(bv, d);
            const int    oi  = __shfl_xor(bi, d);
            const double orw = __shfl_xor(braw, d);
            if (ov > bv || (ov == bv && oi < bi)) { bv = ov; bi = oi; braw = orw; }
        }
        if (rr > 0) mmin = fmin(mmin, prev - bv);
        prev = bv;
        if (rr < 8) {
            wsum += braw;
            if (lane == rr) { my_i = bi; my_w = braw; }
            if ((bi >> 2) == lane) cv[bi & 3] = -1e300;
        }
    }

    const double scale = 2.5 / (wsum + 1e-20);
    if (lane < 8) {
        out_idx[(size_t)t * 8 + lane] = (float)my_i;
        out_w [(size_t)t * 8 + lane] = (float)(my_w * scale);
    }
    const bool flag = (mmin < MTAU) || (gmargin < GTAU);
    if (flag && lane == 0) {
        const int idx = atomicAdd(cnt, 1);
        if (idx < RESCUE_CAP) list[idx] = t;
    }
}

// ---------------------------------------------------------------------------
// K4 v8: fp64 rescue GEMM (verbatim).
// ---------------------------------------------------------------------------
__global__ __launch_bounds__(256, 4)
void rescue_gemm64_v8(const float* __restrict__ x, const float* __restrict__ w,
                      const int* __restrict__ cnt, const int* __restrict__ list,
                      double* __restrict__ resc /* [RESCUE_CAP][N_EXP] */)
{
    const int nf = min(*cnt, RESCUE_CAP);
    const int t0 = blockIdx.y * 32;
    if (t0 >= nf) return;

    __shared__ double xs[32][33];
    __shared__ double wsh[32][33];
    const int tid  = threadIdx.x;
    const int wave = tid >> 6;
    const int lane = tid & 63;
    const int e0 = blockIdx.x * 32;
    const int la = lane & 15;
    const int kq = lane >> 4;

    const double p_idx = (kq == 0) ? (double)la : 0.0;
    const double p_one = (kq == 0) ? 1.0 : 0.0;
    f64x4 prow = (f64x4)(0.0), pcol = (f64x4)(0.0);
    prow = __builtin_amdgcn_mfma_f64_16x16x4f64(p_idx, p_one, prow, 0, 0, 0);
    pcol = __builtin_amdgcn_mfma_f64_16x16x4f64(p_one, p_idx, pcol, 0, 0, 0);
    int rrow[4], rcol[4];
#pragma unroll
    for (int i = 0; i < 4; ++i) {
        rrow[i] = (int)(prow[i] + 0.5);
        rcol[i] = (int)(pcol[i] + 0.5);
    }

    const int r = tid >> 3;     // 0..31
    const int q = tid & 7;
    const int tr = list[min(t0 + r, nf - 1)];
    const float* xp = x + (size_t)tr * HID + q * 4;
    const float* wp = w + (size_t)(e0 + r) * HID + q * 4;

    f64x4 acc = (f64x4)(0.0);
    float4 xv = *(const float4*)xp;
    float4 wv = *(const float4*)wp;
    const int m0 = (wave & 1) * 16;
    const int n0 = (wave >> 1) * 16;

    for (int k0 = 0; k0 < HID; k0 += 32) {
        __syncthreads();
        {
            const float a[4] = {xv.x, xv.y, xv.z, xv.w};
            const float b[4] = {wv.x, wv.y, wv.z, wv.w};
#pragma unroll
            for (int j = 0; j < 4; ++j) {
                xs[4 * q + j][r]  = (double)a[j];
                wsh[4 * q + j][r] = (double)b[j];
            }
        }
        __syncthreads();
        if (k0 + 32 < HID) {
            xv = *(const float4*)(xp + k0 + 32);
            wv = *(const float4*)(wp + k0 + 32);
        }
#pragma unroll
        for (int s = 0; s < 8; ++s) {
            const int kk = s * 4 + kq;
            const double a = xs[kk][m0 + la];
            const double b = wsh[kk][n0 + la];
            acc = __builtin_amdgcn_mfma_f64_16x16x4f64(a, b, acc, 0, 0, 0);
        }
    }

#pragma unroll
    for (int i = 0; i < 4; ++i) {
        const size_t lt = t0 + m0 + rrow[i];
        resc[lt * N_EXP + e0 + n0 + rcol[i]] = 1.0 / (1.0 + exp(-acc[i]));
    }
}

// ---------------------------------------------------------------------------
// K5: fp64 rescue routing (verbatim).
// ---------------------------------------------------------------------------
__global__ __launch_bounds__(256)
void rescue_route(const double* __restrict__ resc, const float* __restrict__ bias,
                  const int* __restrict__ cnt, const int* __restrict__ list,
                  float* __restrict__ out_idx, float* __restrict__ out_w)
{
    const int nf = min(*cnt, RESCUE_CAP);
    const int wave = threadIdx.x >> 6;
    const int lane = threadIdx.x & 63;
    const int i_tok = blockIdx.x * 4 + wave;
    if (i_tok >= nf) return;
    const int t = list[i_tok];
    const double* srow = resc + (size_t)i_tok * N_EXP;

    const float4 bf = *(const float4*)(bias + lane * 4);
    const float bfv[4] = {bf.x, bf.y, bf.z, bf.w};
    double raw[4], v[4];
#pragma unroll
    for (int j = 0; j < 4; ++j) {
        raw[j] = srow[4 * lane + j];
        v[j] = raw[j] + (double)bfv[j];
    }

    double m1 = -1e300, m2 = -1e300;
#pragma unroll
    for (int j = 0; j < 4; ++j) {
        if (v[j] > m1) { m2 = m1; m1 = v[j]; }
        else if (v[j] > m2) { m2 = v[j]; }
    }
#pragma unroll
    for (int d = 1; d <= 4; d <<= 1) {
        const double o1 = __shfl_xor(m1, d);
        const double o2 = __shfl_xor(m2, d);
        if (o1 > m1) { m2 = fmax(m1, o2); m1 = o1; }
        else         { m2 = fmax(m2, o1); }
    }
    const double gsum = m1 + m2;

    double gq[8];
#pragma unroll
    for (int g = 0; g < 8; ++g) gq[g] = __shfl(gsum, g * 8);
    int gm = 0;
#pragma unroll
    for (int rr = 0; rr < 4; ++rr) {
        int best = 0; double bv = -1e300;
#pragma unroll
        for (int g = 0; g < 8; ++g) {
            const bool taken = (gm >> g) & 1;
            if (!taken && gq[g] > bv) { bv = gq[g]; best = g; }
        }
        gm |= (1 << best);
    }

    double cv[4];
    const bool inmask = (gm >> (lane >> 3)) & 1;
#pragma unroll
    for (int j = 0; j < 4; ++j) cv[j] = inmask ? v[j] : 0.0;

    double wsum = 0.0, my_w = 0.0;
    int my_i = 0;
#pragma unroll
    for (int rr = 0; rr < 8; ++rr) {
        double bv = cv[0]; int bj = 0;
#pragma unroll
        for (int j = 1; j < 4; ++j)
            if (cv[j] > bv) { bv = cv[j]; bj = j; }
        int bi = 4 * lane + bj;
        double braw = (bj == 0) ? raw[0] : (bj == 1) ? raw[1] : (bj == 2) ? raw[2] : raw[3];
#pragma unroll
        for (int d = 1; d < 64; d <<= 1) {
            const double ov  = __shfl_xor(bv, d);
            const int    oi  = __shfl_xor(bi, d);
            const double orw = __shfl_xor(braw, d);
            if (ov > bv || (ov == bv && oi < bi)) { bv = ov; bi = oi; braw = orw; }
        }
        wsum += braw;
        if (lane == rr) { my_i = bi; my_w = braw; }
        if ((bi >> 2) == lane) cv[bi & 3] = -1e300;
    }

    const double scale = 2.5 / (wsum + 1e-20);
    if (lane < 8) {
        out_idx[(size_t)t * 8 + lane] = (float)my_i;
        out_w [(size_t)t * 8 + lane] = (float)(my_w * scale);
    }
}

extern "C" void kernel_launch(void* const* d_in, const int* in_sizes, int n_in,
                              void* d_out, int out_size, void* d_ws, size_t ws_size,
                              hipStream_t stream)
{
    const float* x    = (const float*)d_in[0];
    const float* w    = (const float*)d_in[1];
    const float* bias = (const float*)d_in[2];
    float* out = (float*)d_out;

    char* ws = (char*)d_ws;
    float*  logits = (float*)ws;                       // 8,388,608 B
    double* resc   = (double*)ws;                      // alias: logits dead after route_flag
    u16*    wh     = (u16*)(ws + 8388608);             // 3,670,016 B
    u16*    wl     = (u16*)(ws + 12058624);            // 3,670,016 B
    int*    cnt    = (int*)(ws + 15728640);
    int*    list   = (int*)(ws + 15728704);            // 2048*4

    zero_cnt<<<1, 64, 0, stream>>>(cnt);
    zero_logits<<<(T_TOK * N_EXP) / (256 * 4), 256, 0, stream>>>(logits);
    wsplit<<<(N_EXP * HID) / (256 * 8), 256, 0, stream>>>(w, wh, wl);
    gemm_bf16split_v9<<<512, 256, 0, stream>>>(x, wh, wl, logits);
    route_flag<<<T_TOK / 4, 256, 0, stream>>>(logits, bias, out, out + (size_t)T_TOK * 8, cnt, list);
    rescue_gemm64_v8<<<dim3(N_EXP / 32, RESCUE_CAP / 32), 256, 0, stream>>>(x, w, cnt, list, resc);
    rescue_route<<<RESCUE_CAP / 4, 256, 0, stream>>>(resc, bias, cnt, list, out, out + (size_t)T_TOK * 8);
}

// Round 2
// 615.409 us; speedup vs baseline: 1.1028x; 1.0844x over previous
//
#include <hip/hip_runtime.h>
#include <cmath>

#define T_TOK 8192
#define N_EXP 256
#define HID   7168
#define KHALF 3584
#define RESCUE_CAP 2048
#define MTAU 4e-5     // expert-chain margin threshold (score space), ~3x the 5-sigma bf16-split error
#define GTAU 1.6e-4   // group-sum margin threshold (= 4*MTAU)

typedef unsigned short u16;
typedef short bf16x8 __attribute__((ext_vector_type(8)));
typedef short s16x4 __attribute__((ext_vector_type(4)));
typedef float f32x4 __attribute__((ext_vector_type(4)));
typedef double f64x4 __attribute__((ext_vector_type(4)));

typedef const __attribute__((address_space(1))) unsigned int* gas_ptr;
typedef __attribute__((address_space(3))) unsigned int* las_ptr;

__device__ __forceinline__ u16 bf16_rtne(float f) {
    unsigned u = __float_as_uint(f);
    u += 0x7FFFu + ((u >> 16) & 1u);
    return (u16)(u >> 16);
}
__device__ __forceinline__ float bf16_f(u16 h) { return __uint_as_float(((unsigned)h) << 16); }

// fp32 -> (hi,lo) bf16 pair via native __bf16 casts (v_cvt_pk_bf16_f32, RTNE —
// bit-identical to the manual RTNE twiddle for finite inputs, ~3x fewer VALU ops)
__device__ __forceinline__ void cvt8(float4 a, float4 b, bf16x8& H, bf16x8& L) {
    const float f[8] = {a.x, a.y, a.z, a.w, b.x, b.y, b.z, b.w};
#pragma unroll
    for (int i = 0; i < 8; ++i) {
        const __bf16 h = (__bf16)f[i];
        const u16 hb = __builtin_bit_cast(u16, h);
        H[i] = (short)hb;
        const float hif = __uint_as_float(((unsigned)hb) << 16);
        const __bf16 l = (__bf16)(f[i] - hif);
        L[i] = (short)__builtin_bit_cast(u16, l);
    }
}

// LDS tile [rows][32 bf16] with per-row XOR swizzle of the 16B chunk index:
// physical chunk = c16 ^ ((row>>1)&3). Makes every b128 read/write <=2-way (free).
__device__ __forceinline__ int swz(int row, int c16) {
    return row * 32 + (((c16 ^ (row >> 1)) & 3) << 3);
}

__device__ __forceinline__ void gload16(const void* g, void* l) {
    __builtin_amdgcn_global_load_lds((gas_ptr)g, (las_ptr)l, 16, 0, 0);
}

__global__ __launch_bounds__(256)
void zero_logits(float* __restrict__ p, int* __restrict__ cnt) {
    if (blockIdx.x == 0 && threadIdx.x == 0) *cnt = 0;
    const size_t i = ((size_t)blockIdx.x * 256 + threadIdx.x) * 4;
    *(float4*)(p + i) = make_float4(0.f, 0.f, 0.f, 0.f);
}

// ---------------------------------------------------------------------------
// K1: split w fp32 -> (wh, wl) bf16 pair. Exact: wl = bf16(w - float(wh)).
// ---------------------------------------------------------------------------
__global__ __launch_bounds__(256)
void wsplit(const float* __restrict__ w, u16* __restrict__ wh, u16* __restrict__ wl)
{
    const size_t base = ((size_t)blockIdx.x * 256 + threadIdx.x) * 8;
    const float4 f0 = *(const float4*)(w + base);
    const float4 f1 = *(const float4*)(w + base + 4);
    const float f[8] = {f0.x, f0.y, f0.z, f0.w, f1.x, f1.y, f1.z, f1.w};
    bf16x8 H, L;
#pragma unroll
    for (int i = 0; i < 8; ++i) {
        const u16 h = bf16_rtne(f[i]);
        H[i] = (short)h;
        L[i] = (short)bf16_rtne(f[i] - bf16_f(h));
    }
    *(bf16x8*)(wh + base) = H;
    *(bf16x8*)(wl + base) = L;
}

// ---------------------------------------------------------------------------
// K2 v10: 2-phase software pipeline (T3 minimum recipe).
//  - Full double buffer (x AND w tiles), ONE __syncthreads per k-step.
//  - All next-tile loads (2x global_load_lds for w, 4x float4 for x) issued at
//    the TOP of the iteration; the vmcnt(0) drain implied by the end-of-iter
//    barrier lands a full MFMA+cvt phase later -> load latency hidden.
//  - x conversion via native __bf16 casts (cvt_pk, RTNE) overlapped with MFMA.
//  - Geometry/mapping/swizzle/epilogue identical to v9 (all HW-proven):
//    BM=128 x BN=64, BK=32, 4 waves, K-split x2, XCD-grouped slabs,
//    atomicAdd combine (2 commutative fp32 adds/cell -> deterministic).
// ---------------------------------------------------------------------------
__global__ __launch_bounds__(256, 2)
void gemm_bf16split_v10(const float* __restrict__ x, const u16* __restrict__ wh,
                        const u16* __restrict__ wl, float* __restrict__ logits)
{
    __shared__ u16 sxh[2][128 * 32], sxl[2][128 * 32];
    __shared__ u16 swh[2][64 * 32],  swl[2][64 * 32];
    const int tid = threadIdx.x;
    const int wave = tid >> 6, lane = tid & 63;

    // block mapping: h%8 selects slab-group lane -> slab j handled by XCD j&7
    const int h = blockIdx.x;
    const int cc8 = (h >> 3) & 7;              // 8 blocks per slab
    const int col = cc8 & 3, kz = cc8 >> 2;    // 4 expert cols x 2 k-halves
    const int slab = (h & 7) | ((h >> 6) << 3);
    const int t0 = slab * 128;
    const int e0 = col * 64;
    const int kbase = kz * KHALF;

    const int la = lane & 15, q = lane >> 4;

    // calibration probes: decode C/D reg->(row,col) on-device (v8-proven)
    bf16x8 pidx = (bf16x8)(short)0, pone = (bf16x8)(short)0;
    if (q == 0) {
        pidx[0] = (short)bf16_rtne((float)la);
        pone[0] = (short)0x3F80;
    }
    f32x4 pr = __builtin_amdgcn_mfma_f32_16x16x32_bf16(pidx, pone, (f32x4)(0.f), 0, 0, 0);
    f32x4 pc = __builtin_amdgcn_mfma_f32_16x16x32_bf16(pone, pidx, (f32x4)(0.f), 0, 0, 0);
    int rrow[4], rcol[4];
#pragma unroll
    for (int i = 0; i < 4; ++i) {
        rrow[i] = (int)(pr[i] + 0.5f);
        rcol[i] = (int)(pc[i] + 0.5f);
    }

    // x staging coords: thread -> row sr (0..127), k-half halfk (16 floats)
    const int sr = tid >> 1, halfk = tid & 1;
    const float* xp = x + (size_t)(t0 + sr) * HID + kbase + halfk * 16;

    // w staging via global_load_lds: dest = wave-uniform base + lane*16
    // lane's LDS slot: row = wave*16 + (lane>>2), chunk = lane&3;
    // source chunk pre-swizzled so swizzled reads retrieve logical data.
    const int wlr = wave * 16 + (lane >> 2);
    const int wgc = (lane & 3) ^ ((wlr >> 1) & 3);
    const u16* whp = wh + (size_t)(e0 + wlr) * HID + kbase + wgc * 8;
    const u16* wlp = wl + (size_t)(e0 + wlr) * HID + kbase + wgc * 8;

    f32x4 acc[4][2];
#pragma unroll
    for (int i = 0; i < 4; ++i)
#pragma unroll
        for (int j = 0; j < 2; ++j) acc[i][j] = (f32x4)(0.f);

    const int m0 = (wave >> 1) * 64;
    const int n0 = (wave & 1) * 32;

    // ---- prologue: stage tile 0 into buffer 0 ----
    gload16(whp, &swh[0][wave * 512]);
    gload16(wlp, &swl[0][wave * 512]);
    {
        float4 a = *(const float4*)xp,       b = *(const float4*)(xp + 4);
        float4 c = *(const float4*)(xp + 8), d = *(const float4*)(xp + 12);
        bf16x8 XH0, XH1, XL0, XL1;
        cvt8(a, b, XH0, XL0);
        cvt8(c, d, XH1, XL1);
        *(bf16x8*)&sxh[0][swz(sr, 2 * halfk)]     = XH0;
        *(bf16x8*)&sxh[0][swz(sr, 2 * halfk + 1)] = XH1;
        *(bf16x8*)&sxl[0][swz(sr, 2 * halfk)]     = XL0;
        *(bf16x8*)&sxl[0][swz(sr, 2 * halfk + 1)] = XL1;
    }
    __syncthreads();   // drains vmcnt (w0 DMA) + lgkm (x0 writes)

    int cur = 0;
    for (int k0 = 0; k0 < KHALF; k0 += 32) {
        const int nxt = cur ^ 1;
        const bool more = (k0 + 32 < KHALF);
        float4 xa, xb, xc, xd;
        // --- top: issue ALL next-tile loads (drained only at end-of-iter barrier)
        if (more) {
            gload16(whp + k0 + 32, &swh[nxt][wave * 512]);
            gload16(wlp + k0 + 32, &swl[nxt][wave * 512]);
            const float* p = xp + k0 + 32;
            xa = *(const float4*)p;       xb = *(const float4*)(p + 4);
            xc = *(const float4*)(p + 8); xd = *(const float4*)(p + 12);
        }
        // --- compute tile `cur`
        bf16x8 Ah[4], Al[4], Bh[2], Bl[2];
#pragma unroll
        for (int mi = 0; mi < 4; ++mi) {
            const int r = m0 + 16 * mi + la;
            Ah[mi] = *(const bf16x8*)&sxh[cur][swz(r, q)];
            Al[mi] = *(const bf16x8*)&sxl[cur][swz(r, q)];
        }
#pragma unroll
        for (int ni = 0; ni < 2; ++ni) {
            const int r = n0 + 16 * ni + la;
            Bh[ni] = *(const bf16x8*)&swh[cur][swz(r, q)];
            Bl[ni] = *(const bf16x8*)&swl[cur][swz(r, q)];
        }
#pragma unroll
        for (int mi = 0; mi < 4; ++mi)
#pragma unroll
            for (int ni = 0; ni < 2; ++ni) {
                acc[mi][ni] = __builtin_amdgcn_mfma_f32_16x16x32_bf16(Ah[mi], Bh[ni], acc[mi][ni], 0, 0, 0);
                acc[mi][ni] = __builtin_amdgcn_mfma_f32_16x16x32_bf16(Ah[mi], Bl[ni], acc[mi][ni], 0, 0, 0);
                acc[mi][ni] = __builtin_amdgcn_mfma_f32_16x16x32_bf16(Al[mi], Bh[ni], acc[mi][ni], 0, 0, 0);
            }
        // --- late: convert + stage next x tile (x-load latency hidden by MFMA)
        if (more) {
            bf16x8 XH0, XH1, XL0, XL1;
            cvt8(xa, xb, XH0, XL0);
            cvt8(xc, xd, XH1, XL1);
            *(bf16x8*)&sxh[nxt][swz(sr, 2 * halfk)]     = XH0;
            *(bf16x8*)&sxh[nxt][swz(sr, 2 * halfk + 1)] = XH1;
            *(bf16x8*)&sxl[nxt][swz(sr, 2 * halfk)]     = XL0;
            *(bf16x8*)&sxl[nxt][swz(sr, 2 * halfk + 1)] = XL1;
        }
        __syncthreads();   // ONE barrier/k-step: drains w DMA (issued a phase ago) + x writes
        cur = nxt;
    }

    // k-split combine: exactly 2 contributions per cell onto zeroed memory;
    // fp32 add is commutative -> bitwise deterministic.
#pragma unroll
    for (int mi = 0; mi < 4; ++mi)
#pragma unroll
        for (int ni = 0; ni < 2; ++ni)
#pragma unroll
            for (int i = 0; i < 4; ++i)
                atomicAdd(&logits[(size_t)(t0 + m0 + 16 * mi + rrow[i]) * N_EXP + e0 + n0 + 16 * ni + rcol[i]],
                          acc[mi][ni][i]);
}

// ---------------------------------------------------------------------------
// K3: routing + margin flags (verbatim r7-proven).
// ---------------------------------------------------------------------------
__global__ __launch_bounds__(256)
void route_flag(const float* __restrict__ logits, const float* __restrict__ bias,
                float* __restrict__ out_idx, float* __restrict__ out_w,
                int* __restrict__ cnt, int* __restrict__ list)
{
    const int wave = threadIdx.x >> 6;
    const int lane = threadIdx.x & 63;
    const int t = blockIdx.x * 4 + wave;

    const float4 lg = *(const float4*)(logits + (size_t)t * N_EXP + 4 * lane);
    const float4 bf = *(const float4*)(bias + 4 * lane);
    const float lgv[4] = {lg.x, lg.y, lg.z, lg.w};
    const float bfv[4] = {bf.x, bf.y, bf.z, bf.w};
    double raw[4], v[4];
#pragma unroll
    for (int j = 0; j < 4; ++j) {
        raw[j] = 1.0 / (1.0 + exp(-(double)lgv[j]));
        v[j] = raw[j] + (double)bfv[j];
    }

    double m1 = -1e300, m2 = -1e300;
#pragma unroll
    for (int j = 0; j < 4; ++j) {
        if (v[j] > m1) { m2 = m1; m1 = v[j]; }
        else if (v[j] > m2) { m2 = v[j]; }
    }
#pragma unroll
    for (int d = 1; d <= 4; d <<= 1) {
        const double o1 = __shfl_xor(m1, d);
        const double o2 = __shfl_xor(m2, d);
        if (o1 > m1) { m2 = fmax(m1, o2); m1 = o1; }
        else         { m2 = fmax(m2, o1); }
    }
    const double gsum = m1 + m2;

    double gq[8];
#pragma unroll
    for (int g = 0; g < 8; ++g) gq[g] = __shfl(gsum, g * 8);
    int gm = 0;
    double g4v = -1e300, gmargin = 1e300;
#pragma unroll
    for (int rr = 0; rr < 5; ++rr) {
        int best = 0; double bv = -1e300;
#pragma unroll
        for (int g = 0; g < 8; ++g) {
            const bool taken = (gm >> g) & 1;
            if (!taken && gq[g] > bv) { bv = gq[g]; best = g; }
        }
        if (rr < 4) { gm |= (1 << best); g4v = bv; }
        else gmargin = g4v - bv;
    }

    double cv[4];
    const bool inmask = (gm >> (lane >> 3)) & 1;
#pragma unroll
    for (int j = 0; j < 4; ++j) cv[j] = inmask ? v[j] : 0.0;

    double wsum = 0.0, my_w = 0.0, prev = 0.0, mmin = 1e300;
    int my_i = 0;
#pragma unroll
    for (int rr = 0; rr < 9; ++rr) {
        double bv = cv[0]; int bj = 0;
#pragma unroll
        for (int j = 1; j < 4; ++j)
            if (cv[j] > bv) { bv = cv[j]; bj = j; }
        int bi = 4 * lane + bj;
        double braw = (bj == 0) ? raw[0] : (bj == 1) ? raw[1] : (bj == 2) ? raw[2] : raw[3];
#pragma unroll
        for (int d = 1; d < 64; d <<= 1) {
            const double ov  = __shfl_xor(bv, d);
            const int    oi  = __shfl_xor(bi, d);
            const double orw = __shfl_xor(braw, d);
            if (ov > bv || (ov == bv && oi < bi)) { bv = ov; bi = oi; braw = orw; }
        }
        if (rr > 0) mmin = fmin(mmin, prev - bv);
        prev = bv;
        if (rr < 8) {
            wsum += braw;
            if (lane == rr) { my_i = bi; my_w = braw; }
            if ((bi >> 2) == lane) cv[bi & 3] = -1e300;
        }
    }

    const double scale = 2.5 / (wsum + 1e-20);
    if (lane < 8) {
        out_idx[(size_t)t * 8 + lane] = (float)my_i;
        out_w [(size_t)t * 8 + lane] = (float)(my_w * scale);
    }
    const bool flag = (mmin < MTAU) || (gmargin < GTAU);
    if (flag && lane == 0) {
        const int idx = atomicAdd(cnt, 1);
        if (idx < RESCUE_CAP) list[idx] = t;
    }
}

// ---------------------------------------------------------------------------
// K4 v8: fp64 rescue GEMM (verbatim).
// ---------------------------------------------------------------------------
__global__ __launch_bounds__(256, 4)
void rescue_gemm64_v8(const float* __restrict__ x, const float* __restrict__ w,
                      const int* __restrict__ cnt, const int* __restrict__ list,
                      double* __restrict__ resc /* [RESCUE_CAP][N_EXP] */)
{
    const int nf = min(*cnt, RESCUE_CAP);
    const int t0 = blockIdx.y * 32;
    if (t0 >= nf) return;

    __shared__ double xs[32][33];
    __shared__ double wsh[32][33];
    const int tid  = threadIdx.x;
    const int wave = tid >> 6;
    const int lane = tid & 63;
    const int e0 = blockIdx.x * 32;
    const int la = lane & 15;
    const int kq = lane >> 4;

    const double p_idx = (kq == 0) ? (double)la : 0.0;
    const double p_one = (kq == 0) ? 1.0 : 0.0;
    f64x4 prow = (f64x4)(0.0), pcol = (f64x4)(0.0);
    prow = __builtin_amdgcn_mfma_f64_16x16x4f64(p_idx, p_one, prow, 0, 0, 0);
    pcol = __builtin_amdgcn_mfma_f64_16x16x4f64(p_one, p_idx, pcol, 0, 0, 0);
    int rrow[4], rcol[4];
#pragma unroll
    for (int i = 0; i < 4; ++i) {
        rrow[i] = (int)(prow[i] + 0.5);
        rcol[i] = (int)(pcol[i] + 0.5);
    }

    const int r = tid >> 3;     // 0..31
    const int q = tid & 7;
    const int tr = list[min(t0 + r, nf - 1)];
    const float* xp = x + (size_t)tr * HID + q * 4;
    const float* wp = w + (size_t)(e0 + r) * HID + q * 4;

    f64x4 acc = (f64x4)(0.0);
    float4 xv = *(const float4*)xp;
    float4 wv = *(const float4*)wp;
    const int m0 = (wave & 1) * 16;
    const int n0 = (wave >> 1) * 16;

    for (int k0 = 0; k0 < HID; k0 += 32) {
        __syncthreads();
        {
            const float a[4] = {xv.x, xv.y, xv.z, xv.w};
            const float b[4] = {wv.x, wv.y, wv.z, wv.w};
#pragma unroll
            for (int j = 0; j < 4; ++j) {
                xs[4 * q + j][r]  = (double)a[j];
                wsh[4 * q + j][r] = (double)b[j];
            }
        }
        __syncthreads();
        if (k0 + 32 < HID) {
            xv = *(const float4*)(xp + k0 + 32);
            wv = *(const float4*)(wp + k0 + 32);
        }
#pragma unroll
        for (int s = 0; s < 8; ++s) {
            const int kk = s * 4 + kq;
            const double a = xs[kk][m0 + la];
            const double b = wsh[kk][n0 + la];
            acc = __builtin_amdgcn_mfma_f64_16x16x4f64(a, b, acc, 0, 0, 0);
        }
    }

#pragma unroll
    for (int i = 0; i < 4; ++i) {
        const size_t lt = t0 + m0 + rrow[i];
        resc[lt * N_EXP + e0 + n0 + rcol[i]] = 1.0 / (1.0 + exp(-acc[i]));
    }
}

// ---------------------------------------------------------------------------
// K5: fp64 rescue routing (verbatim).
// ---------------------------------------------------------------------------
__global__ __launch_bounds__(256)
void rescue_route(const double* __restrict__ resc, const float* __restrict__ bias,
                  const int* __restrict__ cnt, const int* __restrict__ list,
                  float* __restrict__ out_idx, float* __restrict__ out_w)
{
    const int nf = min(*cnt, RESCUE_CAP);
    const int wave = threadIdx.x >> 6;
    const int lane = threadIdx.x & 63;
    const int i_tok = blockIdx.x * 4 + wave;
    if (i_tok >= nf) return;
    const int t = list[i_tok];
    const double* srow = resc + (size_t)i_tok * N_EXP;

    const float4 bf = *(const float4*)(bias + lane * 4);
    const float bfv[4] = {bf.x, bf.y, bf.z, bf.w};
    double raw[4], v[4];
#pragma unroll
    for (int j = 0; j < 4; ++j) {
        raw[j] = srow[4 * lane + j];
        v[j] = raw[j] + (double)bfv[j];
    }

    double m1 = -1e300, m2 = -1e300;
#pragma unroll
    for (int j = 0; j < 4; ++j) {
        if (v[j] > m1) { m2 = m1; m1 = v[j]; }
        else if (v[j] > m2) { m2 = v[j]; }
    }
#pragma unroll
    for (int d = 1; d <= 4; d <<= 1) {
        const double o1 = __shfl_xor(m1, d);
        const double o2 = __shfl_xor(m2, d);
        if (o1 > m1) { m2 = fmax(m1, o2); m1 = o1; }
        else         { m2 = fmax(m2, o1); }
    }
    const double gsum = m1 + m2;

    double gq[8];
#pragma unroll
    for (int g = 0; g < 8; ++g) gq[g] = __shfl(gsum, g * 8);
    int gm = 0;
#pragma unroll
    for (int rr = 0; rr < 4; ++rr) {
        int best = 0; double bv = -1e300;
#pragma unroll
        for (int g = 0; g < 8; ++g) {
            const bool taken = (gm >> g) & 1;
            if (!taken && gq[g] > bv) { bv = gq[g]; best = g; }
        }
        gm |= (1 << best);
    }

    double cv[4];
    const bool inmask = (gm >> (lane >> 3)) & 1;
#pragma unroll
    for (int j = 0; j < 4; ++j) cv[j] = inmask ? v[j] : 0.0;

    double wsum = 0.0, my_w = 0.0;
    int my_i = 0;
#pragma unroll
    for (int rr = 0; rr < 8; ++rr) {
        double bv = cv[0]; int bj = 0;
#pragma unroll
        for (int j = 1; j < 4; ++j)
            if (cv[j] > bv) { bv = cv[j]; bj = j; }
        int bi = 4 * lane + bj;
        double braw = (bj == 0) ? raw[0] : (bj == 1) ? raw[1] : (bj == 2) ? raw[2] : raw[3];
#pragma unroll
        for (int d = 1; d < 64; d <<= 1) {
            const double ov  = __shfl_xor(bv, d);
            const int    oi  = __shfl_xor(bi, d);
            const double orw = __shfl_xor(braw, d);
            if (ov > bv || (ov == bv && oi < bi)) { bv = ov; bi = oi; braw = orw; }
        }
        wsum += braw;
        if (lane == rr) { my_i = bi; my_w = braw; }
        if ((bi >> 2) == lane) cv[bi & 3] = -1e300;
    }

    const double scale = 2.5 / (wsum + 1e-20);
    if (lane < 8) {
        out_idx[(size_t)t * 8 + lane] = (float)my_i;
        out_w [(size_t)t * 8 + lane] = (float)(my_w * scale);
    }
}

extern "C" void kernel_launch(void* const* d_in, const int* in_sizes, int n_in,
                              void* d_out, int out_size, void* d_ws, size_t ws_size,
                              hipStream_t stream)
{
    const float* x    = (const float*)d_in[0];
    const float* w    = (const float*)d_in[1];
    const float* bias = (const float*)d_in[2];
    float* out = (float*)d_out;

    char* ws = (char*)d_ws;
    float*  logits = (float*)ws;                       // 8,388,608 B
    double* resc   = (double*)ws;                      // alias: logits dead after route_flag
    u16*    wh     = (u16*)(ws + 8388608);             // 3,670,016 B
    u16*    wl     = (u16*)(ws + 12058624);            // 3,670,016 B
    int*    cnt    = (int*)(ws + 15728640);
    int*    list   = (int*)(ws + 15728704);            // 2048*4

    zero_logits<<<(T_TOK * N_EXP) / (256 * 4), 256, 0, stream>>>(logits, cnt);
    wsplit<<<(N_EXP * HID) / (256 * 8), 256, 0, stream>>>(w, wh, wl);
    gemm_bf16split_v10<<<512, 256, 0, stream>>>(x, wh, wl, logits);
    route_flag<<<T_TOK / 4, 256, 0, stream>>>(logits, bias, out, out + (size_t)T_TOK * 8, cnt, list);
    rescue_gemm64_v8<<<dim3(N_EXP / 32, RESCUE_CAP / 32), 256, 0, stream>>>(x, w, cnt, list, resc);
    rescue_route<<<RESCUE_CAP / 4, 256, 0, stream>>>(resc, bias, cnt, list, out, out + (size_t)T_TOK * 8);
}

// Round 3
// 571.592 us; speedup vs baseline: 1.1874x; 1.0767x over previous
//
#include <hip/hip_runtime.h>
#include <cmath>

#define T_TOK 8192
#define N_EXP 256
#define HID   7168
#define KQUART 1792
#define RESCUE_CAP 2048
#define MTAU 4e-5     // expert-chain margin threshold (score space), ~3x the 5-sigma bf16-split error
#define GTAU 1.6e-4   // group-sum margin threshold (= 4*MTAU)

typedef unsigned short u16;
typedef short bf16x8 __attribute__((ext_vector_type(8)));
typedef short s16x4 __attribute__((ext_vector_type(4)));
typedef float f32x4 __attribute__((ext_vector_type(4)));
typedef float f32x16 __attribute__((ext_vector_type(16)));
typedef double f64x4 __attribute__((ext_vector_type(4)));

typedef const __attribute__((address_space(1))) unsigned int* gas_ptr;
typedef __attribute__((address_space(3))) unsigned int* las_ptr;

__device__ __forceinline__ u16 bf16_rtne(float f) {
    unsigned u = __float_as_uint(f);
    u += 0x7FFFu + ((u >> 16) & 1u);
    return (u16)(u >> 16);
}
__device__ __forceinline__ float bf16_f(u16 h) { return __uint_as_float(((unsigned)h) << 16); }

// fp32 -> (hi,lo) bf16 pair via native __bf16 casts (v_cvt_pk_bf16_f32, RTNE —
// bit-identical to the manual RTNE twiddle for finite inputs)
__device__ __forceinline__ void cvt8(float4 a, float4 b, bf16x8& H, bf16x8& L) {
    const float f[8] = {a.x, a.y, a.z, a.w, b.x, b.y, b.z, b.w};
#pragma unroll
    for (int i = 0; i < 8; ++i) {
        const __bf16 h = (__bf16)f[i];
        const u16 hb = __builtin_bit_cast(u16, h);
        H[i] = (short)hb;
        const float hif = __uint_as_float(((unsigned)hb) << 16);
        const __bf16 l = (__bf16)(f[i] - hif);
        L[i] = (short)__builtin_bit_cast(u16, l);
    }
}

// LDS tile [rows][32 bf16] with per-row XOR swizzle of the 16B chunk index:
// physical chunk = c16 ^ ((row>>1)&3). Proven conflict-free (v10: 0 conflicts).
__device__ __forceinline__ int swz(int row, int c16) {
    return row * 32 + (((c16 ^ (row >> 1)) & 3) << 3);
}

__device__ __forceinline__ void gload16(const void* g, void* l) {
    __builtin_amdgcn_global_load_lds((gas_ptr)g, (las_ptr)l, 16, 0, 0);
}

__global__ __launch_bounds__(256)
void zero_logits(float* __restrict__ p, int* __restrict__ cnt) {
    if (blockIdx.x == 0 && threadIdx.x == 0) *cnt = 0;
    const size_t i = ((size_t)blockIdx.x * 256 + threadIdx.x) * 4;
    *(float4*)(p + i) = make_float4(0.f, 0.f, 0.f, 0.f);
}

// ---------------------------------------------------------------------------
// K1: split w fp32 -> (wh, wl) bf16 pair. Exact: wl = bf16(w - float(wh)).
// ---------------------------------------------------------------------------
__global__ __launch_bounds__(256)
void wsplit(const float* __restrict__ w, u16* __restrict__ wh, u16* __restrict__ wl)
{
    const size_t base = ((size_t)blockIdx.x * 256 + threadIdx.x) * 8;
    const float4 f0 = *(const float4*)(w + base);
    const float4 f1 = *(const float4*)(w + base + 4);
    const float f[8] = {f0.x, f0.y, f0.z, f0.w, f1.x, f1.y, f1.z, f1.w};
    bf16x8 H, L;
#pragma unroll
    for (int i = 0; i < 8; ++i) {
        const u16 h = bf16_rtne(f[i]);
        H[i] = (short)h;
        L[i] = (short)bf16_rtne(f[i] - bf16_f(h));
    }
    *(bf16x8*)(wh + base) = H;
    *(bf16x8*)(wl + base) = L;
}

// ---------------------------------------------------------------------------
// K2 v11: 32x32x16 MFMA core (2x FLOP per LDS byte and per instruction).
//  - BM=128 x BN=128, BK=32, 4 waves (2x2), wave tile 64x64 (2x2 of 32x32).
//  - K-split x4 -> grid 512 = 2 blocks/CU; 56 k-steps/block (was 112).
//  - Per k-step: 24 MFMA_32x32 (384 SIMD-cyc) vs 16 ds_read_b128 -> latency
//    toll per barrier amortized over 2x matrix work.
//  - Same proven machinery: single-barrier dbuf pipeline, late cvt, XOR chunk
//    swizzle, global_load_lds w-staging w/ source pre-swizzle, XCD slab
//    grouping (8 blocks/slab = 2 cols x 4 k-quarters).
//  - atomicAdd combine: 4 contributions/cell; order-nondet ~1e-7 in score
//    space, 400x below MTAU -> rescue semantics unchanged.
//  - C/D layout decoded by on-device probes (self-calibrating, as v8-proven).
// ---------------------------------------------------------------------------
__global__ __launch_bounds__(256, 2)
void gemm_bf16split_v11(const float* __restrict__ x, const u16* __restrict__ wh,
                        const u16* __restrict__ wl, float* __restrict__ logits)
{
    __shared__ u16 sxh[2][128 * 32], sxl[2][128 * 32];
    __shared__ u16 swh[2][128 * 32], swl[2][128 * 32];   // 64 KiB total
    const int tid = threadIdx.x;
    const int wave = tid >> 6, lane = tid & 63;

    // block mapping: h&7 -> slab-group lane (XCD), 8 blocks per slab
    const int h = blockIdx.x;
    const int cc8 = (h >> 3) & 7;
    const int col = cc8 & 1, kq = cc8 >> 1;    // 2 expert cols x 4 k-quarters
    const int slab = (h & 7) | ((h >> 6) << 3);
    const int t0 = slab * 128;
    const int e0 = col * 128;
    const int kbase = kq * KQUART;

    const int la32 = lane & 31, ksel = lane >> 5;

    // calibration probes: decode 32x32 C/D reg->(row,col) on-device.
    // pidx plants row-index values at k=0; pone plants 1.0 at k=0.
    bf16x8 pidx = (bf16x8)(short)0, pone = (bf16x8)(short)0;
    if (ksel == 0) {
        pidx[0] = (short)bf16_rtne((float)la32);
        pone[0] = (short)0x3F80;
    }
    f32x16 pr = __builtin_amdgcn_mfma_f32_32x32x16_bf16(pidx, pone, (f32x16)(0.f), 0, 0, 0);
    f32x16 pc = __builtin_amdgcn_mfma_f32_32x32x16_bf16(pone, pidx, (f32x16)(0.f), 0, 0, 0);
    int rrow[16], rcol[16];
#pragma unroll
    for (int i = 0; i < 16; ++i) {
        rrow[i] = (int)(pr[i] + 0.5f);
        rcol[i] = (int)(pc[i] + 0.5f);
    }

    // x staging: thread -> row sr (0..127), k-half halfk (16 floats)
    const int sr = tid >> 1, halfk = tid & 1;
    const float* xp = x + (size_t)(t0 + sr) * HID + kbase + halfk * 16;

    // w staging via global_load_lds: each wave DMAs rows [wave*32, wave*32+32)
    // in two 16-row calls per array. lane: row = R + (lane>>2), chunk = lane&3,
    // source chunk pre-swizzled (row and row+16 share the same swizzle since
    // ((r+16)>>1)&3 == (r>>1)&3).
    const int R0 = wave * 32;
    const int wrow = R0 + (lane >> 2);
    const int wgc = (lane & 3) ^ ((wrow >> 1) & 3);
    const u16* whp0 = wh + (size_t)(e0 + wrow) * HID + kbase + wgc * 8;
    const u16* wlp0 = wl + (size_t)(e0 + wrow) * HID + kbase + wgc * 8;
    const u16* whp1 = whp0 + (size_t)16 * HID;
    const u16* wlp1 = wlp0 + (size_t)16 * HID;
    const int ldsb0 = R0 * 32, ldsb1 = ldsb0 + 512;

    f32x16 acc[2][2];
#pragma unroll
    for (int i = 0; i < 2; ++i)
#pragma unroll
        for (int j = 0; j < 2; ++j) acc[i][j] = (f32x16)(0.f);

    const int m0 = (wave >> 1) * 64;
    const int n0 = (wave & 1) * 64;

    // ---- prologue: stage tile 0 into buffer 0 ----
    gload16(whp0, &swh[0][ldsb0]);
    gload16(whp1, &swh[0][ldsb1]);
    gload16(wlp0, &swl[0][ldsb0]);
    gload16(wlp1, &swl[0][ldsb1]);
    {
        float4 a = *(const float4*)xp,       b = *(const float4*)(xp + 4);
        float4 c = *(const float4*)(xp + 8), d = *(const float4*)(xp + 12);
        bf16x8 XH0, XH1, XL0, XL1;
        cvt8(a, b, XH0, XL0);
        cvt8(c, d, XH1, XL1);
        *(bf16x8*)&sxh[0][swz(sr, 2 * halfk)]     = XH0;
        *(bf16x8*)&sxh[0][swz(sr, 2 * halfk + 1)] = XH1;
        *(bf16x8*)&sxl[0][swz(sr, 2 * halfk)]     = XL0;
        *(bf16x8*)&sxl[0][swz(sr, 2 * halfk + 1)] = XL1;
    }
    __syncthreads();

    int cur = 0;
    for (int k0 = 0; k0 < KQUART; k0 += 32) {
        const int nxt = cur ^ 1;
        const bool more = (k0 + 32 < KQUART);
        float4 xa, xb, xc, xd;
        // --- top: issue ALL next-tile loads (drained only at end-of-iter barrier)
        if (more) {
            gload16(whp0 + k0 + 32, &swh[nxt][ldsb0]);
            gload16(whp1 + k0 + 32, &swh[nxt][ldsb1]);
            gload16(wlp0 + k0 + 32, &swl[nxt][ldsb0]);
            gload16(wlp1 + k0 + 32, &swl[nxt][ldsb1]);
            const float* p = xp + k0 + 32;
            xa = *(const float4*)p;       xb = *(const float4*)(p + 4);
            xc = *(const float4*)(p + 8); xd = *(const float4*)(p + 12);
        }
        // --- compute tile `cur`: 2 k-subs x (2m x 2n) x 3 passes
#pragma unroll
        for (int ksub = 0; ksub < 2; ++ksub) {
            const int ch = 2 * ksub + ksel;
            bf16x8 Ah[2], Al[2], Bh[2], Bl[2];
#pragma unroll
            for (int mi = 0; mi < 2; ++mi) {
                const int r = m0 + 32 * mi + la32;
                Ah[mi] = *(const bf16x8*)&sxh[cur][swz(r, ch)];
                Al[mi] = *(const bf16x8*)&sxl[cur][swz(r, ch)];
            }
#pragma unroll
            for (int ni = 0; ni < 2; ++ni) {
                const int r = n0 + 32 * ni + la32;
                Bh[ni] = *(const bf16x8*)&swh[cur][swz(r, ch)];
                Bl[ni] = *(const bf16x8*)&swl[cur][swz(r, ch)];
            }
#pragma unroll
            for (int mi = 0; mi < 2; ++mi)
#pragma unroll
                for (int ni = 0; ni < 2; ++ni) {
                    acc[mi][ni] = __builtin_amdgcn_mfma_f32_32x32x16_bf16(Ah[mi], Bh[ni], acc[mi][ni], 0, 0, 0);
                    acc[mi][ni] = __builtin_amdgcn_mfma_f32_32x32x16_bf16(Ah[mi], Bl[ni], acc[mi][ni], 0, 0, 0);
                    acc[mi][ni] = __builtin_amdgcn_mfma_f32_32x32x16_bf16(Al[mi], Bh[ni], acc[mi][ni], 0, 0, 0);
                }
        }
        // --- late: convert + stage next x tile (x-load latency hidden by MFMA)
        if (more) {
            bf16x8 XH0, XH1, XL0, XL1;
            cvt8(xa, xb, XH0, XL0);
            cvt8(xc, xd, XH1, XL1);
            *(bf16x8*)&sxh[nxt][swz(sr, 2 * halfk)]     = XH0;
            *(bf16x8*)&sxh[nxt][swz(sr, 2 * halfk + 1)] = XH1;
            *(bf16x8*)&sxl[nxt][swz(sr, 2 * halfk)]     = XL0;
            *(bf16x8*)&sxl[nxt][swz(sr, 2 * halfk + 1)] = XL1;
        }
        __syncthreads();   // ONE barrier/k-step
        cur = nxt;
    }

    // k-split combine: 4 contributions per cell onto zeroed memory.
#pragma unroll
    for (int mi = 0; mi < 2; ++mi)
#pragma unroll
        for (int ni = 0; ni < 2; ++ni)
#pragma unroll
            for (int i = 0; i < 16; ++i)
                atomicAdd(&logits[(size_t)(t0 + m0 + 32 * mi + rrow[i]) * N_EXP + e0 + n0 + 32 * ni + rcol[i]],
                          acc[mi][ni][i]);
}

// ---------------------------------------------------------------------------
// K3: routing + margin flags (verbatim r7-proven).
// ---------------------------------------------------------------------------
__global__ __launch_bounds__(256)
void route_flag(const float* __restrict__ logits, const float* __restrict__ bias,
                float* __restrict__ out_idx, float* __restrict__ out_w,
                int* __restrict__ cnt, int* __restrict__ list)
{
    const int wave = threadIdx.x >> 6;
    const int lane = threadIdx.x & 63;
    const int t = blockIdx.x * 4 + wave;

    const float4 lg = *(const float4*)(logits + (size_t)t * N_EXP + 4 * lane);
    const float4 bf = *(const float4*)(bias + 4 * lane);
    const float lgv[4] = {lg.x, lg.y, lg.z, lg.w};
    const float bfv[4] = {bf.x, bf.y, bf.z, bf.w};
    double raw[4], v[4];
#pragma unroll
    for (int j = 0; j < 4; ++j) {
        raw[j] = 1.0 / (1.0 + exp(-(double)lgv[j]));
        v[j] = raw[j] + (double)bfv[j];
    }

    double m1 = -1e300, m2 = -1e300;
#pragma unroll
    for (int j = 0; j < 4; ++j) {
        if (v[j] > m1) { m2 = m1; m1 = v[j]; }
        else if (v[j] > m2) { m2 = v[j]; }
    }
#pragma unroll
    for (int d = 1; d <= 4; d <<= 1) {
        const double o1 = __shfl_xor(m1, d);
        const double o2 = __shfl_xor(m2, d);
        if (o1 > m1) { m2 = fmax(m1, o2); m1 = o1; }
        else         { m2 = fmax(m2, o1); }
    }
    const double gsum = m1 + m2;

    double gq[8];
#pragma unroll
    for (int g = 0; g < 8; ++g) gq[g] = __shfl(gsum, g * 8);
    int gm = 0;
    double g4v = -1e300, gmargin = 1e300;
#pragma unroll
    for (int rr = 0; rr < 5; ++rr) {
        int best = 0; double bv = -1e300;
#pragma unroll
        for (int g = 0; g < 8; ++g) {
            const bool taken = (gm >> g) & 1;
            if (!taken && gq[g] > bv) { bv = gq[g]; best = g; }
        }
        if (rr < 4) { gm |= (1 << best); g4v = bv; }
        else gmargin = g4v - bv;
    }

    double cv[4];
    const bool inmask = (gm >> (lane >> 3)) & 1;
#pragma unroll
    for (int j = 0; j < 4; ++j) cv[j] = inmask ? v[j] : 0.0;

    double wsum = 0.0, my_w = 0.0, prev = 0.0, mmin = 1e300;
    int my_i = 0;
#pragma unroll
    for (int rr = 0; rr < 9; ++rr) {
        double bv = cv[0]; int bj = 0;
#pragma unroll
        for (int j = 1; j < 4; ++j)
            if (cv[j] > bv) { bv = cv[j]; bj = j; }
        int bi = 4 * lane + bj;
        double braw = (bj == 0) ? raw[0] : (bj == 1) ? raw[1] : (bj == 2) ? raw[2] : raw[3];
#pragma unroll
        for (int d = 1; d < 64; d <<= 1) {
            const double ov  = __shfl_xor(bv, d);
            const int    oi  = __shfl_xor(bi, d);
            const double orw = __shfl_xor(braw, d);
            if (ov > bv || (ov == bv && oi < bi)) { bv = ov; bi = oi; braw = orw; }
        }
        if (rr > 0) mmin = fmin(mmin, prev - bv);
        prev = bv;
        if (rr < 8) {
            wsum += braw;
            if (lane == rr) { my_i = bi; my_w = braw; }
            if ((bi >> 2) == lane) cv[bi & 3] = -1e300;
        }
    }

    const double scale = 2.5 / (wsum + 1e-20);
    if (lane < 8) {
        out_idx[(size_t)t * 8 + lane] = (float)my_i;
        out_w [(size_t)t * 8 + lane] = (float)(my_w * scale);
    }
    const bool flag = (mmin < MTAU) || (gmargin < GTAU);
    if (flag && lane == 0) {
        const int idx = atomicAdd(cnt, 1);
        if (idx < RESCUE_CAP) list[idx] = t;
    }
}

// ---------------------------------------------------------------------------
// K4 v8: fp64 rescue GEMM (verbatim).
// ---------------------------------------------------------------------------
__global__ __launch_bounds__(256, 4)
void rescue_gemm64_v8(const float* __restrict__ x, const float* __restrict__ w,
                      const int* __restrict__ cnt, const int* __restrict__ list,
                      double* __restrict__ resc /* [RESCUE_CAP][N_EXP] */)
{
    const int nf = min(*cnt, RESCUE_CAP);
    const int t0 = blockIdx.y * 32;
    if (t0 >= nf) return;

    __shared__ double xs[32][33];
    __shared__ double wsh[32][33];
    const int tid  = threadIdx.x;
    const int wave = tid >> 6;
    const int lane = tid & 63;
    const int e0 = blockIdx.x * 32;
    const int la = lane & 15;
    const int kq = lane >> 4;

    const double p_idx = (kq == 0) ? (double)la : 0.0;
    const double p_one = (kq == 0) ? 1.0 : 0.0;
    f64x4 prow = (f64x4)(0.0), pcol = (f64x4)(0.0);
    prow = __builtin_amdgcn_mfma_f64_16x16x4f64(p_idx, p_one, prow, 0, 0, 0);
    pcol = __builtin_amdgcn_mfma_f64_16x16x4f64(p_one, p_idx, pcol, 0, 0, 0);
    int rrow[4], rcol[4];
#pragma unroll
    for (int i = 0; i < 4; ++i) {
        rrow[i] = (int)(prow[i] + 0.5);
        rcol[i] = (int)(pcol[i] + 0.5);
    }

    const int r = tid >> 3;     // 0..31
    const int q = tid & 7;
    const int tr = list[min(t0 + r, nf - 1)];
    const float* xp = x + (size_t)tr * HID + q * 4;
    const float* wp = w + (size_t)(e0 + r) * HID + q * 4;

    f64x4 acc = (f64x4)(0.0);
    float4 xv = *(const float4*)xp;
    float4 wv = *(const float4*)wp;
    const int m0 = (wave & 1) * 16;
    const int n0 = (wave >> 1) * 16;

    for (int k0 = 0; k0 < HID; k0 += 32) {
        __syncthreads();
        {
            const float a[4] = {xv.x, xv.y, xv.z, xv.w};
            const float b[4] = {wv.x, wv.y, wv.z, wv.w};
#pragma unroll
            for (int j = 0; j < 4; ++j) {
                xs[4 * q + j][r]  = (double)a[j];
                wsh[4 * q + j][r] = (double)b[j];
            }
        }
        __syncthreads();
        if (k0 + 32 < HID) {
            xv = *(const float4*)(xp + k0 + 32);
            wv = *(const float4*)(wp + k0 + 32);
        }
#pragma unroll
        for (int s = 0; s < 8; ++s) {
            const int kk = s * 4 + kq;
            const double a = xs[kk][m0 + la];
            const double b = wsh[kk][n0 + la];
            acc = __builtin_amdgcn_mfma_f64_16x16x4f64(a, b, acc, 0, 0, 0);
        }
    }

#pragma unroll
    for (int i = 0; i < 4; ++i) {
        const size_t lt = t0 + m0 + rrow[i];
        resc[lt * N_EXP + e0 + n0 + rcol[i]] = 1.0 / (1.0 + exp(-acc[i]));
    }
}

// ---------------------------------------------------------------------------
// K5: fp64 rescue routing (verbatim).
// ---------------------------------------------------------------------------
__global__ __launch_bounds__(256)
void rescue_route(const double* __restrict__ resc, const float* __restrict__ bias,
                  const int* __restrict__ cnt, const int* __restrict__ list,
                  float* __restrict__ out_idx, float* __restrict__ out_w)
{
    const int nf = min(*cnt, RESCUE_CAP);
    const int wave = threadIdx.x >> 6;
    const int lane = threadIdx.x & 63;
    const int i_tok = blockIdx.x * 4 + wave;
    if (i_tok >= nf) return;
    const int t = list[i_tok];
    const double* srow = resc + (size_t)i_tok * N_EXP;

    const float4 bf = *(const float4*)(bias + lane * 4);
    const float bfv[4] = {bf.x, bf.y, bf.z, bf.w};
    double raw[4], v[4];
#pragma unroll
    for (int j = 0; j < 4; ++j) {
        raw[j] = srow[4 * lane + j];
        v[j] = raw[j] + (double)bfv[j];
    }

    double m1 = -1e300, m2 = -1e300;
#pragma unroll
    for (int j = 0; j < 4; ++j) {
        if (v[j] > m1) { m2 = m1; m1 = v[j]; }
        else if (v[j] > m2) { m2 = v[j]; }
    }
#pragma unroll
    for (int d = 1; d <= 4; d <<= 1) {
        const double o1 = __shfl_xor(m1, d);
        const double o2 = __shfl_xor(m2, d);
        if (o1 > m1) { m2 = fmax(m1, o2); m1 = o1; }
        else         { m2 = fmax(m2, o1); }
    }
    const double gsum = m1 + m2;

    double gq[8];
#pragma unroll
    for (int g = 0; g < 8; ++g) gq[g] = __shfl(gsum, g * 8);
    int gm = 0;
#pragma unroll
    for (int rr = 0; rr < 4; ++rr) {
        int best = 0; double bv = -1e300;
#pragma unroll
        for (int g = 0; g < 8; ++g) {
            const bool taken = (gm >> g) & 1;
            if (!taken && gq[g] > bv) { bv = gq[g]; best = g; }
        }
        gm |= (1 << best);
    }

    double cv[4];
    const bool inmask = (gm >> (lane >> 3)) & 1;
#pragma unroll
    for (int j = 0; j < 4; ++j) cv[j] = inmask ? v[j] : 0.0;

    double wsum = 0.0, my_w = 0.0;
    int my_i = 0;
#pragma unroll
    for (int rr = 0; rr < 8; ++rr) {
        double bv = cv[0]; int bj = 0;
#pragma unroll
        for (int j = 1; j < 4; ++j)
            if (cv[j] > bv) { bv = cv[j]; bj = j; }
        int bi = 4 * lane + bj;
        double braw = (bj == 0) ? raw[0] : (bj == 1) ? raw[1] : (bj == 2) ? raw[2] : raw[3];
#pragma unroll
        for (int d = 1; d < 64; d <<= 1) {
            const double ov  = __shfl_xor(bv, d);
            const int    oi  = __shfl_xor(bi, d);
            const double orw = __shfl_xor(braw, d);
            if (ov > bv || (ov == bv && oi < bi)) { bv = ov; bi = oi; braw = orw; }
        }
        wsum += braw;
        if (lane == rr) { my_i = bi; my_w = braw; }
        if ((bi >> 2) == lane) cv[bi & 3] = -1e300;
    }

    const double scale = 2.5 / (wsum + 1e-20);
    if (lane < 8) {
        out_idx[(size_t)t * 8 + lane] = (float)my_i;
        out_w [(size_t)t * 8 + lane] = (float)(my_w * scale);
    }
}

extern "C" void kernel_launch(void* const* d_in, const int* in_sizes, int n_in,
                              void* d_out, int out_size, void* d_ws, size_t ws_size,
                              hipStream_t stream)
{
    const float* x    = (const float*)d_in[0];
    const float* w    = (const float*)d_in[1];
    const float* bias = (const float*)d_in[2];
    float* out = (float*)d_out;

    char* ws = (char*)d_ws;
    float*  logits = (float*)ws;                       // 8,388,608 B
    double* resc   = (double*)ws;                      // alias: logits dead after route_flag
    u16*    wh     = (u16*)(ws + 8388608);             // 3,670,016 B
    u16*    wl     = (u16*)(ws + 12058624);            // 3,670,016 B
    int*    cnt    = (int*)(ws + 15728640);
    int*    list   = (int*)(ws + 15728704);            // 2048*4

    zero_logits<<<(T_TOK * N_EXP) / (256 * 4), 256, 0, stream>>>(logits, cnt);
    wsplit<<<(N_EXP * HID) / (256 * 8), 256, 0, stream>>>(w, wh, wl);
    gemm_bf16split_v11<<<512, 256, 0, stream>>>(x, wh, wl, logits);
    route_flag<<<T_TOK / 4, 256, 0, stream>>>(logits, bias, out, out + (size_t)T_TOK * 8, cnt, list);
    rescue_gemm64_v8<<<dim3(N_EXP / 32, RESCUE_CAP / 32), 256, 0, stream>>>(x, w, cnt, list, resc);
    rescue_route<<<RESCUE_CAP / 4, 256, 0, stream>>>(resc, bias, cnt, list, out, out + (size_t)T_TOK * 8);
}

// Round 4
// 472.426 us; speedup vs baseline: 1.4366x; 1.2099x over previous
//
#include <hip/hip_runtime.h>
#include <cmath>

#define T_TOK 8192
#define N_EXP 256
#define HID   7168
#define KQUART 1792
#define KR    896     // rescue k-split: HID/8
#define RESCUE_CAP 2048
#define MTAU 4e-5     // expert-chain margin threshold (score space), ~3x the 5-sigma bf16-split error
#define GTAU 1.6e-4   // group-sum margin threshold (= 4*MTAU)

typedef unsigned short u16;
typedef short bf16x8 __attribute__((ext_vector_type(8)));
typedef short s16x4 __attribute__((ext_vector_type(4)));
typedef float f32x4 __attribute__((ext_vector_type(4)));
typedef float f32x16 __attribute__((ext_vector_type(16)));
typedef double f64x4 __attribute__((ext_vector_type(4)));

typedef const __attribute__((address_space(1))) unsigned int* gas_ptr;
typedef __attribute__((address_space(3))) unsigned int* las_ptr;

__device__ __forceinline__ u16 bf16_rtne(float f) {
    unsigned u = __float_as_uint(f);
    u += 0x7FFFu + ((u >> 16) & 1u);
    return (u16)(u >> 16);
}
__device__ __forceinline__ float bf16_f(u16 h) { return __uint_as_float(((unsigned)h) << 16); }

// fp32 -> (hi,lo) bf16 pair via native __bf16 casts (v_cvt_pk_bf16_f32, RTNE —
// bit-identical to the manual RTNE twiddle for finite inputs)
__device__ __forceinline__ void cvt8(float4 a, float4 b, bf16x8& H, bf16x8& L) {
    const float f[8] = {a.x, a.y, a.z, a.w, b.x, b.y, b.z, b.w};
#pragma unroll
    for (int i = 0; i < 8; ++i) {
        const __bf16 h = (__bf16)f[i];
        const u16 hb = __builtin_bit_cast(u16, h);
        H[i] = (short)hb;
        const float hif = __uint_as_float(((unsigned)hb) << 16);
        const __bf16 l = (__bf16)(f[i] - hif);
        L[i] = (short)__builtin_bit_cast(u16, l);
    }
}

// LDS tile [rows][32 bf16] with per-row XOR swizzle of the 16B chunk index:
// physical chunk = c16 ^ ((row>>1)&3). Proven conflict-free (v10/v11: 0 conflicts).
__device__ __forceinline__ int swz(int row, int c16) {
    return row * 32 + (((c16 ^ (row >> 1)) & 3) << 3);
}

__device__ __forceinline__ void gload16(const void* g, void* l) {
    __builtin_amdgcn_global_load_lds((gas_ptr)g, (las_ptr)l, 16, 0, 0);
}

__global__ __launch_bounds__(256)
void zero_logits(float* __restrict__ p, int* __restrict__ cnt) {
    if (blockIdx.x == 0 && threadIdx.x == 0) *cnt = 0;
    const size_t i = ((size_t)blockIdx.x * 256 + threadIdx.x) * 4;
    *(float4*)(p + i) = make_float4(0.f, 0.f, 0.f, 0.f);
}

__global__ __launch_bounds__(256)
void zero_resc(float4* __restrict__ p) {
    p[(size_t)blockIdx.x * 256 + threadIdx.x] = make_float4(0.f, 0.f, 0.f, 0.f);
}

// ---------------------------------------------------------------------------
// K1: split w fp32 -> (wh, wl) bf16 pair. Exact: wl = bf16(w - float(wh)).
// ---------------------------------------------------------------------------
__global__ __launch_bounds__(256)
void wsplit(const float* __restrict__ w, u16* __restrict__ wh, u16* __restrict__ wl)
{
    const size_t base = ((size_t)blockIdx.x * 256 + threadIdx.x) * 8;
    const float4 f0 = *(const float4*)(w + base);
    const float4 f1 = *(const float4*)(w + base + 4);
    const float f[8] = {f0.x, f0.y, f0.z, f0.w, f1.x, f1.y, f1.z, f1.w};
    bf16x8 H, L;
#pragma unroll
    for (int i = 0; i < 8; ++i) {
        const u16 h = bf16_rtne(f[i]);
        H[i] = (short)h;
        L[i] = (short)bf16_rtne(f[i] - bf16_f(h));
    }
    *(bf16x8*)(wh + base) = H;
    *(bf16x8*)(wl + base) = L;
}

// ---------------------------------------------------------------------------
// K2 v11: 32x32x16 MFMA core (verbatim — proven in round 3).
// ---------------------------------------------------------------------------
__global__ __launch_bounds__(256, 2)
void gemm_bf16split_v11(const float* __restrict__ x, const u16* __restrict__ wh,
                        const u16* __restrict__ wl, float* __restrict__ logits)
{
    __shared__ u16 sxh[2][128 * 32], sxl[2][128 * 32];
    __shared__ u16 swh[2][128 * 32], swl[2][128 * 32];   // 64 KiB total
    const int tid = threadIdx.x;
    const int wave = tid >> 6, lane = tid & 63;

    // block mapping: h&7 -> slab-group lane (XCD), 8 blocks per slab
    const int h = blockIdx.x;
    const int cc8 = (h >> 3) & 7;
    const int col = cc8 & 1, kq = cc8 >> 1;    // 2 expert cols x 4 k-quarters
    const int slab = (h & 7) | ((h >> 6) << 3);
    const int t0 = slab * 128;
    const int e0 = col * 128;
    const int kbase = kq * KQUART;

    const int la32 = lane & 31, ksel = lane >> 5;

    // calibration probes: decode 32x32 C/D reg->(row,col) on-device.
    bf16x8 pidx = (bf16x8)(short)0, pone = (bf16x8)(short)0;
    if (ksel == 0) {
        pidx[0] = (short)bf16_rtne((float)la32);
        pone[0] = (short)0x3F80;
    }
    f32x16 pr = __builtin_amdgcn_mfma_f32_32x32x16_bf16(pidx, pone, (f32x16)(0.f), 0, 0, 0);
    f32x16 pc = __builtin_amdgcn_mfma_f32_32x32x16_bf16(pone, pidx, (f32x16)(0.f), 0, 0, 0);
    int rrow[16], rcol[16];
#pragma unroll
    for (int i = 0; i < 16; ++i) {
        rrow[i] = (int)(pr[i] + 0.5f);
        rcol[i] = (int)(pc[i] + 0.5f);
    }

    // x staging: thread -> row sr (0..127), k-half halfk (16 floats)
    const int sr = tid >> 1, halfk = tid & 1;
    const float* xp = x + (size_t)(t0 + sr) * HID + kbase + halfk * 16;

    // w staging via global_load_lds: each wave DMAs rows [wave*32, wave*32+32)
    const int R0 = wave * 32;
    const int wrow = R0 + (lane >> 2);
    const int wgc = (lane & 3) ^ ((wrow >> 1) & 3);
    const u16* whp0 = wh + (size_t)(e0 + wrow) * HID + kbase + wgc * 8;
    const u16* wlp0 = wl + (size_t)(e0 + wrow) * HID + kbase + wgc * 8;
    const u16* whp1 = whp0 + (size_t)16 * HID;
    const u16* wlp1 = wlp0 + (size_t)16 * HID;
    const int ldsb0 = R0 * 32, ldsb1 = ldsb0 + 512;

    f32x16 acc[2][2];
#pragma unroll
    for (int i = 0; i < 2; ++i)
#pragma unroll
        for (int j = 0; j < 2; ++j) acc[i][j] = (f32x16)(0.f);

    const int m0 = (wave >> 1) * 64;
    const int n0 = (wave & 1) * 64;

    // ---- prologue: stage tile 0 into buffer 0 ----
    gload16(whp0, &swh[0][ldsb0]);
    gload16(whp1, &swh[0][ldsb1]);
    gload16(wlp0, &swl[0][ldsb0]);
    gload16(wlp1, &swl[0][ldsb1]);
    {
        float4 a = *(const float4*)xp,       b = *(const float4*)(xp + 4);
        float4 c = *(const float4*)(xp + 8), d = *(const float4*)(xp + 12);
        bf16x8 XH0, XH1, XL0, XL1;
        cvt8(a, b, XH0, XL0);
        cvt8(c, d, XH1, XL1);
        *(bf16x8*)&sxh[0][swz(sr, 2 * halfk)]     = XH0;
        *(bf16x8*)&sxh[0][swz(sr, 2 * halfk + 1)] = XH1;
        *(bf16x8*)&sxl[0][swz(sr, 2 * halfk)]     = XL0;
        *(bf16x8*)&sxl[0][swz(sr, 2 * halfk + 1)] = XL1;
    }
    __syncthreads();

    int cur = 0;
    for (int k0 = 0; k0 < KQUART; k0 += 32) {
        const int nxt = cur ^ 1;
        const bool more = (k0 + 32 < KQUART);
        float4 xa, xb, xc, xd;
        if (more) {
            gload16(whp0 + k0 + 32, &swh[nxt][ldsb0]);
            gload16(whp1 + k0 + 32, &swh[nxt][ldsb1]);
            gload16(wlp0 + k0 + 32, &swl[nxt][ldsb0]);
            gload16(wlp1 + k0 + 32, &swl[nxt][ldsb1]);
            const float* p = xp + k0 + 32;
            xa = *(const float4*)p;       xb = *(const float4*)(p + 4);
            xc = *(const float4*)(p + 8); xd = *(const float4*)(p + 12);
        }
#pragma unroll
        for (int ksub = 0; ksub < 2; ++ksub) {
            const int ch = 2 * ksub + ksel;
            bf16x8 Ah[2], Al[2], Bh[2], Bl[2];
#pragma unroll
            for (int mi = 0; mi < 2; ++mi) {
                const int r = m0 + 32 * mi + la32;
                Ah[mi] = *(const bf16x8*)&sxh[cur][swz(r, ch)];
                Al[mi] = *(const bf16x8*)&sxl[cur][swz(r, ch)];
            }
#pragma unroll
            for (int ni = 0; ni < 2; ++ni) {
                const int r = n0 + 32 * ni + la32;
                Bh[ni] = *(const bf16x8*)&swh[cur][swz(r, ch)];
                Bl[ni] = *(const bf16x8*)&swl[cur][swz(r, ch)];
            }
#pragma unroll
            for (int mi = 0; mi < 2; ++mi)
#pragma unroll
                for (int ni = 0; ni < 2; ++ni) {
                    acc[mi][ni] = __builtin_amdgcn_mfma_f32_32x32x16_bf16(Ah[mi], Bh[ni], acc[mi][ni], 0, 0, 0);
                    acc[mi][ni] = __builtin_amdgcn_mfma_f32_32x32x16_bf16(Ah[mi], Bl[ni], acc[mi][ni], 0, 0, 0);
                    acc[mi][ni] = __builtin_amdgcn_mfma_f32_32x32x16_bf16(Al[mi], Bh[ni], acc[mi][ni], 0, 0, 0);
                }
        }
        if (more) {
            bf16x8 XH0, XH1, XL0, XL1;
            cvt8(xa, xb, XH0, XL0);
            cvt8(xc, xd, XH1, XL1);
            *(bf16x8*)&sxh[nxt][swz(sr, 2 * halfk)]     = XH0;
            *(bf16x8*)&sxh[nxt][swz(sr, 2 * halfk + 1)] = XH1;
            *(bf16x8*)&sxl[nxt][swz(sr, 2 * halfk)]     = XL0;
            *(bf16x8*)&sxl[nxt][swz(sr, 2 * halfk + 1)] = XL1;
        }
        __syncthreads();   // ONE barrier/k-step
        cur = nxt;
    }

    // k-split combine: 4 contributions per cell onto zeroed memory.
#pragma unroll
    for (int mi = 0; mi < 2; ++mi)
#pragma unroll
        for (int ni = 0; ni < 2; ++ni)
#pragma unroll
            for (int i = 0; i < 16; ++i)
                atomicAdd(&logits[(size_t)(t0 + m0 + 32 * mi + rrow[i]) * N_EXP + e0 + n0 + 32 * ni + rcol[i]],
                          acc[mi][ni][i]);
}

// ---------------------------------------------------------------------------
// K3: routing + margin flags (verbatim r7-proven).
// ---------------------------------------------------------------------------
__global__ __launch_bounds__(256)
void route_flag(const float* __restrict__ logits, const float* __restrict__ bias,
                float* __restrict__ out_idx, float* __restrict__ out_w,
                int* __restrict__ cnt, int* __restrict__ list)
{
    const int wave = threadIdx.x >> 6;
    const int lane = threadIdx.x & 63;
    const int t = blockIdx.x * 4 + wave;

    const float4 lg = *(const float4*)(logits + (size_t)t * N_EXP + 4 * lane);
    const float4 bf = *(const float4*)(bias + 4 * lane);
    const float lgv[4] = {lg.x, lg.y, lg.z, lg.w};
    const float bfv[4] = {bf.x, bf.y, bf.z, bf.w};
    double raw[4], v[4];
#pragma unroll
    for (int j = 0; j < 4; ++j) {
        raw[j] = 1.0 / (1.0 + exp(-(double)lgv[j]));
        v[j] = raw[j] + (double)bfv[j];
    }

    double m1 = -1e300, m2 = -1e300;
#pragma unroll
    for (int j = 0; j < 4; ++j) {
        if (v[j] > m1) { m2 = m1; m1 = v[j]; }
        else if (v[j] > m2) { m2 = v[j]; }
    }
#pragma unroll
    for (int d = 1; d <= 4; d <<= 1) {
        const double o1 = __shfl_xor(m1, d);
        const double o2 = __shfl_xor(m2, d);
        if (o1 > m1) { m2 = fmax(m1, o2); m1 = o1; }
        else         { m2 = fmax(m2, o1); }
    }
    const double gsum = m1 + m2;

    double gq[8];
#pragma unroll
    for (int g = 0; g < 8; ++g) gq[g] = __shfl(gsum, g * 8);
    int gm = 0;
    double g4v = -1e300, gmargin = 1e300;
#pragma unroll
    for (int rr = 0; rr < 5; ++rr) {
        int best = 0; double bv = -1e300;
#pragma unroll
        for (int g = 0; g < 8; ++g) {
            const bool taken = (gm >> g) & 1;
            if (!taken && gq[g] > bv) { bv = gq[g]; best = g; }
        }
        if (rr < 4) { gm |= (1 << best); g4v = bv; }
        else gmargin = g4v - bv;
    }

    double cv[4];
    const bool inmask = (gm >> (lane >> 3)) & 1;
#pragma unroll
    for (int j = 0; j < 4; ++j) cv[j] = inmask ? v[j] : 0.0;

    double wsum = 0.0, my_w = 0.0, prev = 0.0, mmin = 1e300;
    int my_i = 0;
#pragma unroll
    for (int rr = 0; rr < 9; ++rr) {
        double bv = cv[0]; int bj = 0;
#pragma unroll
        for (int j = 1; j < 4; ++j)
            if (cv[j] > bv) { bv = cv[j]; bj = j; }
        int bi = 4 * lane + bj;
        double braw = (bj == 0) ? raw[0] : (bj == 1) ? raw[1] : (bj == 2) ? raw[2] : raw[3];
#pragma unroll
        for (int d = 1; d < 64; d <<= 1) {
            const double ov  = __shfl_xor(bv, d);
            const int    oi  = __shfl_xor(bi, d);
            const double orw = __shfl_xor(braw, d);
            if (ov > bv || (ov == bv && oi < bi)) { bv = ov; bi = oi; braw = orw; }
        }
        if (rr > 0) mmin = fmin(mmin, prev - bv);
        prev = bv;
        if (rr < 8) {
            wsum += braw;
            if (lane == rr) { my_i = bi; my_w = braw; }
            if ((bi >> 2) == lane) cv[bi & 3] = -1e300;
        }
    }

    const double scale = 2.5 / (wsum + 1e-20);
    if (lane < 8) {
        out_idx[(size_t)t * 8 + lane] = (float)my_i;
        out_w [(size_t)t * 8 + lane] = (float)(my_w * scale);
    }
    const bool flag = (mmin < MTAU) || (gmargin < GTAU);
    if (flag && lane == 0) {
        const int idx = atomicAdd(cnt, 1);
        if (idx < RESCUE_CAP) list[idx] = t;
    }
}

// ---------------------------------------------------------------------------
// K4 v9: fp64 rescue GEMM, K-split x8 + single-barrier double-buffer pipeline.
//  Round-3 profile: v8 was 169 us with only ~40 live blocks (nf~160), 224
//  2-barrier k-steps, ~900cyc exposed HBM latency each. v9: blockIdx.z splits
//  K into 8 chunks (live blocks x8, iters/block 28), loads issued BEFORE the
//  MFMA block, one barrier/iter. Partials atomicAdd'ed (fp64, raw logits)
//  onto zeroed resc; sigmoid moved to rescue_route. fp64 order-noise ~1e-15,
//  ~10 orders below decision margins.
// ---------------------------------------------------------------------------
__global__ __launch_bounds__(256, 2)
void rescue_gemm64_v9(const float* __restrict__ x, const float* __restrict__ w,
                      const int* __restrict__ cnt, const int* __restrict__ list,
                      double* __restrict__ resc /* [RESCUE_CAP][N_EXP] raw logits */)
{
    const int nf = min(*cnt, RESCUE_CAP);
    const int t0 = blockIdx.y * 32;
    if (t0 >= nf) return;

    __shared__ double xs[2][32][33];
    __shared__ double wsh[2][32][33];
    const int tid  = threadIdx.x;
    const int wave = tid >> 6;
    const int lane = tid & 63;
    const int e0 = blockIdx.x * 32;
    const int kbase = blockIdx.z * KR;
    const int la = lane & 15;
    const int kq = lane >> 4;

    const double p_idx = (kq == 0) ? (double)la : 0.0;
    const double p_one = (kq == 0) ? 1.0 : 0.0;
    f64x4 prow = (f64x4)(0.0), pcol = (f64x4)(0.0);
    prow = __builtin_amdgcn_mfma_f64_16x16x4f64(p_idx, p_one, prow, 0, 0, 0);
    pcol = __builtin_amdgcn_mfma_f64_16x16x4f64(p_one, p_idx, pcol, 0, 0, 0);
    int rrow[4], rcol[4];
#pragma unroll
    for (int i = 0; i < 4; ++i) {
        rrow[i] = (int)(prow[i] + 0.5);
        rcol[i] = (int)(pcol[i] + 0.5);
    }

    const int r = tid >> 3;     // 0..31
    const int q = tid & 7;
    const int tr = list[min(t0 + r, nf - 1)];
    const float* xp = x + (size_t)tr * HID + kbase + q * 4;
    const float* wp = w + (size_t)(e0 + r) * HID + kbase + q * 4;

    f64x4 acc = (f64x4)(0.0);
    const int m0 = (wave & 1) * 16;
    const int n0 = (wave >> 1) * 16;

    // prologue: stage k-chunk 0 into buffer 0
    {
        const float4 xv = *(const float4*)xp;
        const float4 wv = *(const float4*)wp;
        const float a[4] = {xv.x, xv.y, xv.z, xv.w};
        const float b[4] = {wv.x, wv.y, wv.z, wv.w};
#pragma unroll
        for (int j = 0; j < 4; ++j) {
            xs[0][4 * q + j][r]  = (double)a[j];
            wsh[0][4 * q + j][r] = (double)b[j];
        }
    }
    __syncthreads();

    int cur = 0;
    for (int k0 = 0; k0 < KR; k0 += 32) {
        const int nxt = cur ^ 1;
        const bool more = (k0 + 32 < KR);
        float4 xv, wv;
        // issue next-chunk loads BEFORE compute (latency hidden under MFMAs)
        if (more) {
            xv = *(const float4*)(xp + k0 + 32);
            wv = *(const float4*)(wp + k0 + 32);
        }
#pragma unroll
        for (int s = 0; s < 8; ++s) {
            const int kk = s * 4 + kq;
            const double a = xs[cur][kk][m0 + la];
            const double b = wsh[cur][kk][n0 + la];
            acc = __builtin_amdgcn_mfma_f64_16x16x4f64(a, b, acc, 0, 0, 0);
        }
        if (more) {
            const float a[4] = {xv.x, xv.y, xv.z, xv.w};
            const float b[4] = {wv.x, wv.y, wv.z, wv.w};
#pragma unroll
            for (int j = 0; j < 4; ++j) {
                xs[nxt][4 * q + j][r]  = (double)a[j];
                wsh[nxt][4 * q + j][r] = (double)b[j];
            }
        }
        __syncthreads();   // ONE barrier/iter
        cur = nxt;
    }

#pragma unroll
    for (int i = 0; i < 4; ++i) {
        const size_t lt = t0 + m0 + rrow[i];
        atomicAdd(&resc[lt * N_EXP + e0 + n0 + rcol[i]], acc[i]);
    }
}

// ---------------------------------------------------------------------------
// K5: fp64 rescue routing. v2: resc now holds raw logits (K-split partial
// sums) -> apply sigmoid here; rest verbatim.
// ---------------------------------------------------------------------------
__global__ __launch_bounds__(256)
void rescue_route(const double* __restrict__ resc, const float* __restrict__ bias,
                  const int* __restrict__ cnt, const int* __restrict__ list,
                  float* __restrict__ out_idx, float* __restrict__ out_w)
{
    const int nf = min(*cnt, RESCUE_CAP);
    const int wave = threadIdx.x >> 6;
    const int lane = threadIdx.x & 63;
    const int i_tok = blockIdx.x * 4 + wave;
    if (i_tok >= nf) return;
    const int t = list[i_tok];
    const double* srow = resc + (size_t)i_tok * N_EXP;

    const float4 bf = *(const float4*)(bias + lane * 4);
    const float bfv[4] = {bf.x, bf.y, bf.z, bf.w};
    double raw[4], v[4];
#pragma unroll
    for (int j = 0; j < 4; ++j) {
        raw[j] = 1.0 / (1.0 + exp(-srow[4 * lane + j]));
        v[j] = raw[j] + (double)bfv[j];
    }

    double m1 = -1e300, m2 = -1e300;
#pragma unroll
    for (int j = 0; j < 4; ++j) {
        if (v[j] > m1) { m2 = m1; m1 = v[j]; }
        else if (v[j] > m2) { m2 = v[j]; }
    }
#pragma unroll
    for (int d = 1; d <= 4; d <<= 1) {
        const double o1 = __shfl_xor(m1, d);
        const double o2 = __shfl_xor(m2, d);
        if (o1 > m1) { m2 = fmax(m1, o2); m1 = o1; }
        else         { m2 = fmax(m2, o1); }
    }
    const double gsum = m1 + m2;

    double gq[8];
#pragma unroll
    for (int g = 0; g < 8; ++g) gq[g] = __shfl(gsum, g * 8);
    int gm = 0;
#pragma unroll
    for (int rr = 0; rr < 4; ++rr) {
        int best = 0; double bv = -1e300;
#pragma unroll
        for (int g = 0; g < 8; ++g) {
            const bool taken = (gm >> g) & 1;
            if (!taken && gq[g] > bv) { bv = gq[g]; best = g; }
        }
        gm |= (1 << best);
    }

    double cv[4];
    const bool inmask = (gm >> (lane >> 3)) & 1;
#pragma unroll
    for (int j = 0; j < 4; ++j) cv[j] = inmask ? v[j] : 0.0;

    double wsum = 0.0, my_w = 0.0;
    int my_i = 0;
#pragma unroll
    for (int rr = 0; rr < 8; ++rr) {
        double bv = cv[0]; int bj = 0;
#pragma unroll
        for (int j = 1; j < 4; ++j)
            if (cv[j] > bv) { bv = cv[j]; bj = j; }
        int bi = 4 * lane + bj;
        double braw = (bj == 0) ? raw[0] : (bj == 1) ? raw[1] : (bj == 2) ? raw[2] : raw[3];
#pragma unroll
        for (int d = 1; d < 64; d <<= 1) {
            const double ov  = __shfl_xor(bv, d);
            const int    oi  = __shfl_xor(bi, d);
            const double orw = __shfl_xor(braw, d);
            if (ov > bv || (ov == bv && oi < bi)) { bv = ov; bi = oi; braw = orw; }
        }
        wsum += braw;
        if (lane == rr) { my_i = bi; my_w = braw; }
        if ((bi >> 2) == lane) cv[bi & 3] = -1e300;
    }

    const double scale = 2.5 / (wsum + 1e-20);
    if (lane < 8) {
        out_idx[(size_t)t * 8 + lane] = (float)my_i;
        out_w [(size_t)t * 8 + lane] = (float)(my_w * scale);
    }
}

extern "C" void kernel_launch(void* const* d_in, const int* in_sizes, int n_in,
                              void* d_out, int out_size, void* d_ws, size_t ws_size,
                              hipStream_t stream)
{
    const float* x    = (const float*)d_in[0];
    const float* w    = (const float*)d_in[1];
    const float* bias = (const float*)d_in[2];
    float* out = (float*)d_out;

    char* ws = (char*)d_ws;
    float*  logits = (float*)ws;                       // 8,388,608 B
    double* resc   = (double*)ws;                      // alias: logits dead after route_flag
    u16*    wh     = (u16*)(ws + 8388608);             // 3,670,016 B
    u16*    wl     = (u16*)(ws + 12058624);            // 3,670,016 B
    int*    cnt    = (int*)(ws + 15728640);
    int*    list   = (int*)(ws + 15728704);            // 2048*4

    zero_logits<<<(T_TOK * N_EXP) / (256 * 4), 256, 0, stream>>>(logits, cnt);
    wsplit<<<(N_EXP * HID) / (256 * 8), 256, 0, stream>>>(w, wh, wl);
    gemm_bf16split_v11<<<512, 256, 0, stream>>>(x, wh, wl, logits);
    route_flag<<<T_TOK / 4, 256, 0, stream>>>(logits, bias, out, out + (size_t)T_TOK * 8, cnt, list);
    // resc aliases logits -> zero AFTER route_flag consumed logits
    zero_resc<<<(RESCUE_CAP * N_EXP * 8) / (16 * 256), 256, 0, stream>>>((float4*)resc);
    rescue_gemm64_v9<<<dim3(N_EXP / 32, RESCUE_CAP / 32, HID / KR), 256, 0, stream>>>(x, w, cnt, list, resc);
    rescue_route<<<RESCUE_CAP / 4, 256, 0, stream>>>(resc, bias, cnt, list, out, out + (size_t)T_TOK * 8);
}